// Round 7
// baseline (728.817 us; speedup 1.0000x reference)
//
#include <hip/hip_runtime.h>

#define SEQ 512
#define BATCH 128
#define DIM 1024
#define T 32

__device__ __forceinline__ float rlf(float x, int n) {
    return __int_as_float(__builtin_amdgcn_readlane(__float_as_int(x), n));
}

// wave-uniform mask bit: 512 bits in 8 u64 (SGPR-resident), cselect tree + shift
__device__ __forceinline__ int mbit(unsigned long long m0, unsigned long long m1,
        unsigned long long m2, unsigned long long m3, unsigned long long m4,
        unsigned long long m5, unsigned long long m6, unsigned long long m7, int i) {
    int w = i >> 6;
    unsigned long long cm =
        (w < 4) ? ((w < 2) ? (w == 0 ? m0 : m1) : (w == 2 ? m2 : m3))
                : ((w < 6) ? (w == 4 ? m4 : m5) : (w == 6 ? m6 : m7));
    return (int)((cm >> (i & 63)) & 1ULL);
}

#define BALLOTS(pre, bb) \
    unsigned long long pre##0 = __ballot(mask[(0 * 64 + tid) * BATCH + (bb)] != 0); \
    unsigned long long pre##1 = __ballot(mask[(1 * 64 + tid) * BATCH + (bb)] != 0); \
    unsigned long long pre##2 = __ballot(mask[(2 * 64 + tid) * BATCH + (bb)] != 0); \
    unsigned long long pre##3 = __ballot(mask[(3 * 64 + tid) * BATCH + (bb)] != 0); \
    unsigned long long pre##4 = __ballot(mask[(4 * 64 + tid) * BATCH + (bb)] != 0); \
    unsigned long long pre##5 = __ballot(mask[(5 * 64 + tid) * BATCH + (bb)] != 0); \
    unsigned long long pre##6 = __ballot(mask[(6 * 64 + tid) * BATCH + (bb)] != 0); \
    unsigned long long pre##7 = __ballot(mask[(7 * 64 + tid) * BATCH + (bb)] != 0);

#define MB(pre, i) mbit(pre##0, pre##1, pre##2, pre##3, pre##4, pre##5, pre##6, pre##7, (i))

// 32-source matvec via readlane: q = sum_n rlf(src, n) * Et[n]
#define MATVEC32(dst, src, Et) { \
    float q0 = 0.f, q1 = 0.f, q2 = 0.f, q3 = 0.f; \
    _Pragma("unroll") \
    for (int n = 0; n < 8; ++n) { \
        q0 = fmaf(rlf(src, 4 * n + 0), Et[4 * n + 0], q0); \
        q1 = fmaf(rlf(src, 4 * n + 1), Et[4 * n + 1], q1); \
        q2 = fmaf(rlf(src, 4 * n + 2), Et[4 * n + 2], q2); \
        q3 = fmaf(rlf(src, 4 * n + 3), Et[4 * n + 3], q3); \
    } \
    dst = (q0 + q1) + (q2 + q3); }

#define RLSUM32(dst, src) { \
    float s0 = 0.f, s1 = 0.f, s2 = 0.f, s3 = 0.f; \
    _Pragma("unroll") \
    for (int n = 0; n < 8; ++n) { \
        s0 += rlf(src, 4 * n + 0); \
        s1 += rlf(src, 4 * n + 1); \
        s2 += rlf(src, 4 * n + 2); \
        s3 += rlf(src, 4 * n + 3); \
    } \
    dst = (s0 + s1) + (s2 + s3); }

// ---------------- W transpose: Wt[d][t] = W[t][d] ----------------
__global__ void k_wt(const float* __restrict__ W, float* __restrict__ Wt)
{
    int idx = blockIdx.x * 256 + threadIdx.x;   // 32768 total
    if (idx >= DIM * T) return;
    int d = idx >> 5, t = idx & 31;
    Wt[idx] = W[t * DIM + d];
}

// ---------------- emissions (unchanged) ----------------
__global__ __launch_bounds__(256) void k_emis(const float* __restrict__ A,
        const float* __restrict__ Wt, const float* __restrict__ bias,
        float* __restrict__ e)
{
    __shared__ float lds[64 * 37];
    int tid = threadIdx.x;
    int row0 = blockIdx.x * 64;
    int row = tid & 63;
    int grp = __builtin_amdgcn_readfirstlane(tid >> 6);   // 0..3, wave-uniform
    int q = tid & 7;
    int rb = tid >> 3;

    float acc[8];
    #pragma unroll
    for (int t = 0; t < 8; ++t) acc[t] = bias[grp * 8 + t];

    const float* A0 = &A[(size_t)(row0 + rb) * DIM];
    const float* A1 = &A[(size_t)(row0 + rb + 32) * DIM];

    float4 v0 = *(const float4*)&A0[q * 4];
    float4 v1 = *(const float4*)&A1[q * 4];

    for (int ck = 0; ck < 32; ++ck) {
        lds[rb * 37 + q * 4 + 0] = v0.x;
        lds[rb * 37 + q * 4 + 1] = v0.y;
        lds[rb * 37 + q * 4 + 2] = v0.z;
        lds[rb * 37 + q * 4 + 3] = v0.w;
        lds[(rb + 32) * 37 + q * 4 + 0] = v1.x;
        lds[(rb + 32) * 37 + q * 4 + 1] = v1.y;
        lds[(rb + 32) * 37 + q * 4 + 2] = v1.z;
        lds[(rb + 32) * 37 + q * 4 + 3] = v1.w;
        __syncthreads();
        if (ck < 31) {
            v0 = *(const float4*)&A0[(ck + 1) * 32 + q * 4];
            v1 = *(const float4*)&A1[(ck + 1) * 32 + q * 4];
        }
        #pragma unroll
        for (int d = 0; d < 32; ++d) {
            float av = lds[row * 37 + d];
            const float* wrow = &Wt[(ck * 32 + d) * T + grp * 8];
            #pragma unroll
            for (int t = 0; t < 8; ++t)
                acc[t] = fmaf(av, wrow[t], acc[t]);
        }
        __syncthreads();
    }

    float4* eo = (float4*)&e[(size_t)(row0 + row) * T + grp * 8];
    float4 o0, o1;
    o0.x = acc[0]; o0.y = acc[1]; o0.z = acc[2]; o0.w = acc[3];
    o1.x = acc[4]; o1.y = acc[5]; o1.z = acc[6]; o1.w = acc[7];
    eo[0] = o0; eo[1] = o1;
}

// ---------------- recursions ----------------
// blocks 0..63: alpha, 2 chains/wave (b=2w,2w+1), LDS-buffered output, flush/16 steps
// blocks 64..127: beta, same
// blocks 128..255: viterbi, 1 chain/wave (no per-step global traffic anyway)
__global__ __launch_bounds__(64) void k_rec(const float* __restrict__ e,
        const int* __restrict__ mask,
        const float* __restrict__ trans,
        const float* __restrict__ start,
        const float* __restrict__ endp,
        float* __restrict__ pa, float* __restrict__ pb,
        double* __restrict__ Ca, double* __restrict__ Cb,
        double* __restrict__ zd,
        float* __restrict__ tags_out)
{
    __shared__ __align__(16) char smem[16384];
    int bid = blockIdx.x;
    int tid = threadIdx.x;
    int j   = tid & 31;

    if (bid < 128) {
        int role = bid >> 6;          // 0=alpha, 1=beta
        int w    = bid & 63;
        int bA = 2 * w, bB = 2 * w + 1;
        float* bufA = (float*)smem;                    // [16][32]
        float* bufB = bufA + 512;                      // [16][32]
        double* cbA = (double*)(smem + 4096);          // [16]
        double* cbB = cbA + 16;                        // [16]

        BALLOTS(ma, bA);
        BALLOTS(mb, bB);

        float Et[32];
        float pA, pB;
        double CA, CB;
        float efA[8], efB[8];

        if (role == 0) {
            #pragma unroll
            for (int n = 0; n < 32; ++n) Et[n] = __expf(trans[n * T + j]);
            // init i=0
            float sA = start[j];
            float aA = e[(0 * BATCH + bA) * T + j] + sA;
            float aB = e[(0 * BATCH + bB) * T + j] + sA;
            float mA = aA, mB = aB;
            #pragma unroll
            for (int d = 1; d < 32; d <<= 1) {
                mA = fmaxf(mA, __shfl_xor(mA, d));
                mB = fmaxf(mB, __shfl_xor(mB, d));
            }
            float vA = __expf(aA - mA), vB = __expf(aB - mB);
            float sSA = vA, sSB = vB;
            #pragma unroll
            for (int d = 1; d < 32; d <<= 1) {
                sSA += __shfl_xor(sSA, d);
                sSB += __shfl_xor(sSB, d);
            }
            pA = vA / sSA; pB = vB / sSB;
            CA = (double)mA + (double)__logf(sSA);
            CB = (double)mB + (double)__logf(sSB);
            if (tid < 32) {
                pa[(size_t)(0 * BATCH + bA) * T + j] = pA;
                pa[(size_t)(0 * BATCH + bB) * T + j] = pB;
            }
            if (tid == 0) { Ca[bA] = CA; Ca[bB] = CB; }

            #pragma unroll
            for (int u = 0; u < 8; ++u) {
                efA[u] = e[(size_t)((1 + u) * BATCH + bA) * T + j];
                efB[u] = e[(size_t)((1 + u) * BATCH + bB) * T + j];
            }

            for (int g = 0; g < 64; ++g) {
                int lim = (g < 63) ? 8 : 7;
                #pragma unroll
                for (int u = 0; u < 8; ++u) {
                    if (u >= lim) break;
                    int i = 1 + 8 * g + u;
                    float eeA = __expf(efA[u]);
                    float eeB = __expf(efB[u]);
                    int inx = i + 8; inx = inx < SEQ ? inx : SEQ - 1;
                    efA[u] = e[(size_t)(inx * BATCH + bA) * T + j];
                    efB[u] = e[(size_t)(inx * BATCH + bB) * T + j];
                    float qA, qB;
                    MATVEC32(qA, pA, Et);
                    MATVEC32(qB, pB, Et);
                    if (MB(ma, i)) pA = qA * eeA;
                    if (MB(mb, i)) pB = qB * eeB;
                    int r = (i - 1) & 15;
                    bufA[r * 32 + j] = pA;      // all 64 lanes, dup halves benign
                    bufB[r * 32 + j] = pB;
                    if (tid == 0) { cbA[r] = CA; cbB[r] = CB; }
                }
                // rescale both chains
                float ssA, ssB;
                RLSUM32(ssA, pA);
                RLSUM32(ssB, pB);
                pA = pA / ssA; pB = pB / ssB;
                CA += (double)__logf(ssA);
                CB += (double)__logf(ssB);
                // flush 16 rows every other group
                if ((g & 1) && g < 63) {
                    int ibase = 8 * (g - 1) + 1;
                    int r = tid >> 2, c4 = tid & 3;
                    float4 xA = *(const float4*)&bufA[r * 32 + c4 * 4];
                    float4 xB = *(const float4*)&bufB[r * 32 + c4 * 4];
                    *(float4*)&pa[(size_t)((ibase + r) * BATCH + bA) * T + c4 * 4] = xA;
                    *(float4*)&pa[(size_t)((ibase + r) * BATCH + bB) * T + c4 * 4] = xB;
                    if (tid < 16) Ca[(size_t)(ibase + tid) * BATCH + bA] = cbA[tid];
                    else if (tid < 32) Ca[(size_t)(ibase + tid - 16) * BATCH + bB] = cbB[tid - 16];
                }
            }
            // final flush: i = 497..511 -> rows r = 0..14
            {
                int r = tid >> 2, c4 = tid & 3;
                if (r < 15) {
                    float4 xA = *(const float4*)&bufA[r * 32 + c4 * 4];
                    float4 xB = *(const float4*)&bufB[r * 32 + c4 * 4];
                    *(float4*)&pa[(size_t)((497 + r) * BATCH + bA) * T + c4 * 4] = xA;
                    *(float4*)&pa[(size_t)((497 + r) * BATCH + bB) * T + c4 * 4] = xB;
                }
                if (tid < 15) Ca[(size_t)(497 + tid) * BATCH + bA] = cbA[tid];
                else if (tid >= 16 && tid < 31) Ca[(size_t)(497 + tid - 16) * BATCH + bB] = cbB[tid - 16];
            }
            // fused z
            float ez = __expf(endp[j]);
            float szA, szB, tA = pA * ez, tB = pB * ez;
            RLSUM32(szA, tA);
            RLSUM32(szB, tB);
            if (tid == 0) {
                zd[bA] = CA + (double)__logf(szA);
                zd[bB] = CB + (double)__logf(szB);
            }
        } else {
            // ---- beta ----
            #pragma unroll
            for (int n = 0; n < 32; ++n) Et[n] = __expf(trans[j * T + n]);
            float v0 = endp[j];
            float m = v0;
            #pragma unroll
            for (int d = 1; d < 32; d <<= 1) m = fmaxf(m, __shfl_xor(m, d));
            float v = __expf(v0 - m);
            float s = v;
            #pragma unroll
            for (int d = 1; d < 32; d <<= 1) s += __shfl_xor(s, d);
            pA = v / s; pB = pA;
            CA = (double)m + (double)__logf(s); CB = CA;
            if (tid < 32) {
                pb[(size_t)((SEQ - 1) * BATCH + bA) * T + j] = pA;
                pb[(size_t)((SEQ - 1) * BATCH + bB) * T + j] = pB;
            }
            if (tid == 0) {
                Cb[(size_t)(SEQ - 1) * BATCH + bA] = CA;
                Cb[(size_t)(SEQ - 1) * BATCH + bB] = CB;
            }

            #pragma unroll
            for (int u = 0; u < 8; ++u) {
                efA[u] = e[(size_t)((SEQ - 1 - u) * BATCH + bA) * T + j];
                efB[u] = e[(size_t)((SEQ - 1 - u) * BATCH + bB) * T + j];
            }

            for (int g = 0; g < 64; ++g) {
                int lim = (g < 63) ? 8 : 7;
                #pragma unroll
                for (int u = 0; u < 8; ++u) {
                    if (u >= lim) break;
                    int i = SEQ - 1 - (8 * g + u);      // 511 down to 1
                    float eeA = __expf(efA[u]);
                    float eeB = __expf(efB[u]);
                    int inx = i - 8; inx = inx > 0 ? inx : 0;
                    efA[u] = e[(size_t)(inx * BATCH + bA) * T + j];
                    efB[u] = e[(size_t)(inx * BATCH + bB) * T + j];
                    float peA = pA * eeA, peB = pB * eeB;
                    float qA, qB;
                    MATVEC32(qA, peA, Et);
                    MATVEC32(qB, peB, Et);
                    if (MB(ma, i)) pA = qA;
                    if (MB(mb, i)) pB = qB;
                    int r = (8 * g + u) & 15;
                    bufA[r * 32 + j] = pA;
                    bufB[r * 32 + j] = pB;
                    if (tid == 0) { cbA[r] = CA; cbB[r] = CB; }
                }
                float ssA, ssB;
                RLSUM32(ssA, pA);
                RLSUM32(ssB, pB);
                pA = pA / ssA; pB = pB / ssB;
                CA += (double)__logf(ssA);
                CB += (double)__logf(ssB);
                if ((g & 1) && g < 63) {
                    int obase = 510 - 8 * (g - 1);      // out row for r=0
                    int r = tid >> 2, c4 = tid & 3;
                    float4 xA = *(const float4*)&bufA[r * 32 + c4 * 4];
                    float4 xB = *(const float4*)&bufB[r * 32 + c4 * 4];
                    *(float4*)&pb[(size_t)((obase - r) * BATCH + bA) * T + c4 * 4] = xA;
                    *(float4*)&pb[(size_t)((obase - r) * BATCH + bB) * T + c4 * 4] = xB;
                    if (tid < 16) Cb[(size_t)(obase - tid) * BATCH + bA] = cbA[tid];
                    else if (tid < 32) Cb[(size_t)(obase - (tid - 16)) * BATCH + bB] = cbB[tid - 16];
                }
            }
            // final flush: s=496..510 -> out rows 14..0 (o = 14 - r)
            {
                int r = tid >> 2, c4 = tid & 3;
                if (r < 15) {
                    float4 xA = *(const float4*)&bufA[r * 32 + c4 * 4];
                    float4 xB = *(const float4*)&bufB[r * 32 + c4 * 4];
                    *(float4*)&pb[(size_t)((14 - r) * BATCH + bA) * T + c4 * 4] = xA;
                    *(float4*)&pb[(size_t)((14 - r) * BATCH + bB) * T + c4 * 4] = xB;
                }
                if (tid < 15) Cb[(size_t)(14 - tid) * BATCH + bA] = cbA[tid];
                else if (tid >= 16 && tid < 31) Cb[(size_t)(14 - (tid - 16)) * BATCH + bB] = cbB[tid - 16];
            }
        }
    } else {
        // ---- viterbi (single chain per wave, unchanged structure) ----
        int b = bid - 128;
        unsigned char* hist = (unsigned char*)smem;     // (SEQ-1)*T bytes

        BALLOTS(ma, b);

        float trv[32];
        #pragma unroll
        for (int n = 0; n < 32; ++n)
            trv[n] = trans[n * T + j];

        float sc = start[j] + e[(0 * BATCH + b) * T + j];

        float ef[8];
        #pragma unroll
        for (int u = 0; u < 8; ++u)
            ef[u] = e[(size_t)((1 + u) * BATCH + b) * T + j];

        for (int g = 0; g < 64; ++g) {
            int i0 = 1 + 8 * g;
            int lim = (g < 63) ? 8 : 7;
            #pragma unroll
            for (int u = 0; u < 8; ++u) {
                if (u >= lim) break;
                int i = i0 + u;
                float ej = ef[u];
                int inx = i + 8; inx = inx < SEQ ? inx : SEQ - 1;
                ef[u] = e[(size_t)(inx * BATCH + b) * T + j];
                float c_[32];
                #pragma unroll
                for (int n = 0; n < 32; ++n)
                    c_[n] = (rlf(sc, n) + trv[n]) + ej;
                float v1[16]; int i1[16];
                #pragma unroll
                for (int n = 0; n < 16; ++n) {
                    bool t = c_[2 * n] >= c_[2 * n + 1];
                    v1[n] = t ? c_[2 * n] : c_[2 * n + 1];
                    i1[n] = t ? 2 * n : 2 * n + 1;
                }
                float v2[8]; int i2[8];
                #pragma unroll
                for (int n = 0; n < 8; ++n) {
                    bool t = v1[2 * n] >= v1[2 * n + 1];
                    v2[n] = t ? v1[2 * n] : v1[2 * n + 1];
                    i2[n] = t ? i1[2 * n] : i1[2 * n + 1];
                }
                float v3[4]; int i3[4];
                #pragma unroll
                for (int n = 0; n < 4; ++n) {
                    bool t = v2[2 * n] >= v2[2 * n + 1];
                    v3[n] = t ? v2[2 * n] : v2[2 * n + 1];
                    i3[n] = t ? i2[2 * n] : i2[2 * n + 1];
                }
                float v4[2]; int i4[2];
                #pragma unroll
                for (int n = 0; n < 2; ++n) {
                    bool t = v3[2 * n] >= v3[2 * n + 1];
                    v4[n] = t ? v3[2 * n] : v3[2 * n + 1];
                    i4[n] = t ? i3[2 * n] : i3[2 * n + 1];
                }
                bool t = v4[0] >= v4[1];
                float best = t ? v4[0] : v4[1];
                int bi = t ? i4[0] : i4[1];

                if (tid < 32) hist[(i - 1) * T + j] = (unsigned char)bi;
                if (MB(ma, i)) sc = best;
            }
        }
        // last = argmax_j(score + end), first index on ties
        float fs = sc + endp[j];
        int fj = j;
        #pragma unroll
        for (int d = 1; d < 32; d <<= 1) {
            float ov = __shfl_xor(fs, d);
            int oj = __shfl_xor(fj, d);
            if (ov > fs || (ov == fs && oj < fj)) { fs = ov; fj = oj; }
        }
        __syncthreads();
        if (tid == 0) {
            int tag = fj;
            tags_out[(SEQ - 1) * BATCH + b] = (float)tag;
            for (int i = SEQ - 2; i >= 0; --i) {
                tag = hist[i * T + tag];
                tags_out[i * BATCH + b] = (float)tag;
            }
        }
    }
}

// ---------------- probs = pa * pb * exp(Ca + Cb - z) ----------------
__global__ __launch_bounds__(256) void k_probs(const float* __restrict__ pa,
        const float* __restrict__ pb, const double* __restrict__ Ca,
        const double* __restrict__ Cb, const double* __restrict__ zd,
        float* __restrict__ out)
{
    int idx = blockIdx.x * 256 + threadIdx.x;   // float4 index, 524288 total
    int ib = idx >> 3;                          // (i*BATCH + b)
    int b = ib & (BATCH - 1);
    double ex = Ca[ib] + Cb[ib] - zd[b];
    double scl = exp(ex);
    float4 a = ((const float4*)pa)[idx];
    float4 c = ((const float4*)pb)[idx];
    float4 o;
    o.x = (float)((double)a.x * (double)c.x * scl);
    o.y = (float)((double)a.y * (double)c.y * scl);
    o.z = (float)((double)a.z * (double)c.z * scl);
    o.w = (float)((double)a.w * (double)c.w * scl);
    ((float4*)out)[idx] = o;
}

extern "C" void kernel_launch(void* const* d_in, const int* in_sizes, int n_in,
                              void* d_out, int out_size, void* d_ws, size_t ws_size,
                              hipStream_t stream) {
    const float* features = (const float*)d_in[0];
    const int*   mask     = (const int*)d_in[1];
    const float* W        = (const float*)d_in[2];
    const float* bias     = (const float*)d_in[3];
    const float* trans    = (const float*)d_in[4];
    const float* startp   = (const float*)d_in[5];
    const float* endp     = (const float*)d_in[6];

    char* ws = (char*)d_ws;
    double* Ca = (double*)(ws + 0);                      // 65536 doubles
    double* Cb = (double*)(ws + 524288);                 // 65536 doubles
    double* zd = (double*)(ws + 1048576);                // 128 doubles
    float*  Wt = (float*)(ws + 1049600);                 // 32768 floats
    float*  e  = (float*)(ws + 1180672);                 // 2097152 floats
    float*  pa = (float*)(ws + 9569280);                 // 2097152 floats
    float*  pb = (float*)(ws + 17957888);                // 2097152 floats

    float* probs_out = (float*)d_out;
    float* tags_out  = probs_out + (size_t)SEQ * BATCH * T;

    k_wt<<<128, 256, 0, stream>>>(W, Wt);
    k_emis<<<1024, 256, 0, stream>>>(features, Wt, bias, e);
    k_rec<<<256, 64, 0, stream>>>(e, mask, trans, startp, endp,
                                  pa, pb, Ca, Cb, zd, tags_out);
    k_probs<<<2048, 256, 0, stream>>>(pa, pb, Ca, Cb, zd, probs_out);
}

// Round 9
// 349.149 us; speedup vs baseline: 2.0874x; 2.0874x over previous
//
#include <hip/hip_runtime.h>

#define SEQ 512
#define BATCH 128
#define DIM 1024
#define T 32

__device__ __forceinline__ float rlf(float x, int n) {
    return __int_as_float(__builtin_amdgcn_readlane(__float_as_int(x), n));
}

// wave-uniform mask bit: 512 bits in 8 u64 (SGPR-resident), cselect tree + shift
__device__ __forceinline__ int mbit(unsigned long long m0, unsigned long long m1,
        unsigned long long m2, unsigned long long m3, unsigned long long m4,
        unsigned long long m5, unsigned long long m6, unsigned long long m7, int i) {
    int w = i >> 6;
    unsigned long long cm =
        (w < 4) ? ((w < 2) ? (w == 0 ? m0 : m1) : (w == 2 ? m2 : m3))
                : ((w < 6) ? (w == 4 ? m4 : m5) : (w == 6 ? m6 : m7));
    return (int)((cm >> (i & 63)) & 1ULL);
}

#define BALLOTS(pre, bb) \
    unsigned long long pre##0 = __ballot(mask[(0 * 64 + tid) * BATCH + (bb)] != 0); \
    unsigned long long pre##1 = __ballot(mask[(1 * 64 + tid) * BATCH + (bb)] != 0); \
    unsigned long long pre##2 = __ballot(mask[(2 * 64 + tid) * BATCH + (bb)] != 0); \
    unsigned long long pre##3 = __ballot(mask[(3 * 64 + tid) * BATCH + (bb)] != 0); \
    unsigned long long pre##4 = __ballot(mask[(4 * 64 + tid) * BATCH + (bb)] != 0); \
    unsigned long long pre##5 = __ballot(mask[(5 * 64 + tid) * BATCH + (bb)] != 0); \
    unsigned long long pre##6 = __ballot(mask[(6 * 64 + tid) * BATCH + (bb)] != 0); \
    unsigned long long pre##7 = __ballot(mask[(7 * 64 + tid) * BATCH + (bb)] != 0);

#define MB(pre, i) mbit(pre##0, pre##1, pre##2, pre##3, pre##4, pre##5, pre##6, pre##7, (i))

#define MATVEC32(dst, src, Et) { \
    float q0 = 0.f, q1 = 0.f, q2 = 0.f, q3 = 0.f; \
    _Pragma("unroll") \
    for (int n = 0; n < 8; ++n) { \
        q0 = fmaf(rlf(src, 4 * n + 0), Et[4 * n + 0], q0); \
        q1 = fmaf(rlf(src, 4 * n + 1), Et[4 * n + 1], q1); \
        q2 = fmaf(rlf(src, 4 * n + 2), Et[4 * n + 2], q2); \
        q3 = fmaf(rlf(src, 4 * n + 3), Et[4 * n + 3], q3); \
    } \
    dst = (q0 + q1) + (q2 + q3); }

#define RLSUM32(dst, src) { \
    float s0 = 0.f, s1 = 0.f, s2 = 0.f, s3 = 0.f; \
    _Pragma("unroll") \
    for (int n = 0; n < 8; ++n) { \
        s0 += rlf(src, 4 * n + 0); \
        s1 += rlf(src, 4 * n + 1); \
        s2 += rlf(src, 4 * n + 2); \
        s3 += rlf(src, 4 * n + 3); \
    } \
    dst = (s0 + s1) + (s2 + s3); }

// stage e rows [blk*128, blk*128+127] into ebuf[blk&1] (bulk, between chunks)
#define STAGE(blk) do { \
    _Pragma("unroll") \
    for (int ps = 0; ps < 16; ++ps) { \
        int r = ps * 8 + r8; \
        float4 v = *(const float4*)&e[(size_t)(((blk) * 128 + r) * BATCH + b) * T + q * 4]; \
        *(float4*)&ebuf[(blk) & 1][r * 32 + q * 4] = v; \
    } } while (0)

// flush p rows + C for output block blk from pbuf/cbuf[blk&1]
#define FLUSHPC(dstP, dstC, blk) do { \
    _Pragma("unroll") \
    for (int ps = 0; ps < 16; ++ps) { \
        int r = ps * 8 + r8; \
        float4 v = *(const float4*)&pbuf[(blk) & 1][r * 32 + q * 4]; \
        *(float4*)&dstP[(size_t)(((blk) * 128 + r) * BATCH + b) * T + q * 4] = v; \
    } \
    _Pragma("unroll") \
    for (int ps = 0; ps < 2; ++ps) { \
        int r = ps * 64 + tid; \
        dstC[(size_t)((blk) * 128 + r) * BATCH + b] = cbuf[(blk) & 1][r]; \
    } } while (0)

// ---------------- W transpose: Wt[d][t] = W[t][d] ----------------
__global__ void k_wt(const float* __restrict__ W, float* __restrict__ Wt)
{
    int idx = blockIdx.x * 256 + threadIdx.x;   // 32768 total
    if (idx >= DIM * T) return;
    int d = idx >> 5, t = idx & 31;
    Wt[idx] = W[t * DIM + d];
}

// ---------------- emissions (unchanged) ----------------
__global__ __launch_bounds__(256) void k_emis(const float* __restrict__ A,
        const float* __restrict__ Wt, const float* __restrict__ bias,
        float* __restrict__ e)
{
    __shared__ float lds[64 * 37];
    int tid = threadIdx.x;
    int row0 = blockIdx.x * 64;
    int row = tid & 63;
    int grp = __builtin_amdgcn_readfirstlane(tid >> 6);
    int q = tid & 7;
    int rb = tid >> 3;

    float acc[8];
    #pragma unroll
    for (int t = 0; t < 8; ++t) acc[t] = bias[grp * 8 + t];

    const float* A0 = &A[(size_t)(row0 + rb) * DIM];
    const float* A1 = &A[(size_t)(row0 + rb + 32) * DIM];

    float4 v0 = *(const float4*)&A0[q * 4];
    float4 v1 = *(const float4*)&A1[q * 4];

    for (int ck = 0; ck < 32; ++ck) {
        lds[rb * 37 + q * 4 + 0] = v0.x;
        lds[rb * 37 + q * 4 + 1] = v0.y;
        lds[rb * 37 + q * 4 + 2] = v0.z;
        lds[rb * 37 + q * 4 + 3] = v0.w;
        lds[(rb + 32) * 37 + q * 4 + 0] = v1.x;
        lds[(rb + 32) * 37 + q * 4 + 1] = v1.y;
        lds[(rb + 32) * 37 + q * 4 + 2] = v1.z;
        lds[(rb + 32) * 37 + q * 4 + 3] = v1.w;
        __syncthreads();
        if (ck < 31) {
            v0 = *(const float4*)&A0[(ck + 1) * 32 + q * 4];
            v1 = *(const float4*)&A1[(ck + 1) * 32 + q * 4];
        }
        #pragma unroll
        for (int d = 0; d < 32; ++d) {
            float av = lds[row * 37 + d];
            const float* wrow = &Wt[(ck * 32 + d) * T + grp * 8];
            #pragma unroll
            for (int t = 0; t < 8; ++t)
                acc[t] = fmaf(av, wrow[t], acc[t]);
        }
        __syncthreads();
    }

    float4* eo = (float4*)&e[(size_t)(row0 + row) * T + grp * 8];
    float4 o0, o1;
    o0.x = acc[0]; o0.y = acc[1]; o0.z = acc[2]; o0.w = acc[3];
    o1.x = acc[4]; o1.y = acc[5]; o1.z = acc[6]; o1.w = acc[7];
    eo[0] = o0; eo[1] = o1;
}

// ---------------- recursions: blocks 0..127 alpha, 128..255 beta, 256..383 viterbi ----------------
// Serial loops touch registers+LDS ONLY. Beta chunking fixed from round 8:
// chunks are now 128 steps (511..384, 383..256, 255..128, 127..1) — round 8
// skipped i=384/256/128, leaving output rows 383/255/127 uninitialized.
__global__ __launch_bounds__(64) void k_rec(const float* __restrict__ e,
        const int* __restrict__ mask,
        const float* __restrict__ trans,
        const float* __restrict__ start,
        const float* __restrict__ endp,
        float* __restrict__ pa, float* __restrict__ pb,
        double* __restrict__ Ca, double* __restrict__ Cb,
        double* __restrict__ zd,
        float* __restrict__ tags_out)
{
    __shared__ float  ebuf[2][128 * 32];    // 32 KB e chunk ping-pong
    __shared__ float  pbuf[2][128 * 32];    // 32 KB p-rows ping-pong (viterbi: hist)
    __shared__ double cbuf[2][128];         // 2 KB C-rows
    __shared__ int    tagbuf[SEQ];          // 2 KB (viterbi tags)

    int bid = blockIdx.x;
    int tid = threadIdx.x;
    int j   = tid & 31;
    int role = bid >> 7;
    int b    = bid & 127;
    int r8 = tid >> 3, q = tid & 7;

    BALLOTS(ma, b);

    if (role == 0) {
        // ---- alpha ----
        float Et[32];
        #pragma unroll
        for (int n = 0; n < 32; ++n) Et[n] = __expf(trans[n * T + j]);

        STAGE(0);
        float a0 = ebuf[0][j] + start[j];
        float m = a0;
        #pragma unroll
        for (int d = 1; d < 32; d <<= 1) m = fmaxf(m, __shfl_xor(m, d));
        float v = __expf(a0 - m);
        float s = v;
        #pragma unroll
        for (int d = 1; d < 32; d <<= 1) s += __shfl_xor(s, d);
        float p = v / s;
        double C = (double)m + (double)__logf(s);
        if (tid < 32) pbuf[0][j] = p;
        if (tid == 0) cbuf[0][0] = C;

        for (int c = 0; c < 4; ++c) {
            int i0 = c ? c * 128 : 1, i1 = c * 128 + 127;
            for (int i = i0; i <= i1; ++i) {
                float eraw = ebuf[c & 1][(i & 127) * 32 + j];   // latency hidden under matvec
                float q_;
                MATVEC32(q_, p, Et);
                float ee = __expf(eraw);
                float vv = q_ * ee;
                if (MB(ma, i)) p = vv;
                if (tid < 32) pbuf[c & 1][(i & 127) * 32 + j] = p;
                if (tid == 0) cbuf[c & 1][i & 127] = C;
                if ((i & 7) == 0) {
                    float ss; RLSUM32(ss, p);
                    p = p / ss; C += (double)__logf(ss);
                }
            }
            if (c < 3) STAGE(c + 1);
            FLUSHPC(pa, Ca, c);
        }
        float sz0 = p * __expf(endp[j]);
        float sz; RLSUM32(sz, sz0);
        if (tid == 0) zd[b] = C + (double)__logf(sz);
    } else if (role == 1) {
        // ---- beta ----
        float Et[32];
        #pragma unroll
        for (int n = 0; n < 32; ++n) Et[n] = __expf(trans[j * T + n]);

        STAGE(3);
        float v0 = endp[j];
        float m = v0;
        #pragma unroll
        for (int d = 1; d < 32; d <<= 1) m = fmaxf(m, __shfl_xor(m, d));
        float v = __expf(v0 - m);
        float s = v;
        #pragma unroll
        for (int d = 1; d < 32; d <<= 1) s += __shfl_xor(s, d);
        float p = v / s;
        double C = (double)m + (double)__logf(s);
        if (tid < 32) pbuf[1][127 * 32 + j] = p;
        if (tid == 0) cbuf[1][127] = C;

        float eraw = ebuf[1][127 * 32 + j];   // e row 511, consumed at step 511
        for (int c = 0; c < 4; ++c) {
            int iS = 511 - 128 * c;                    // 511, 383, 255, 127
            int iE = (c < 3) ? (384 - 128 * c) : 1;    // 384, 256, 128, 1
            for (int i = iS; i >= iE; --i) {
                float ee = __expf(eraw);
                if (i > iE)   // in-chunk prefetch of row i-1 (same staged buffer)
                    eraw = ebuf[((i - 1) >> 7) & 1][((i - 1) & 127) * 32 + j];
                float pe = p * ee;
                float q_;
                MATVEC32(q_, pe, Et);
                if (MB(ma, i)) p = q_;
                int orow = i - 1, lb = (orow >> 7) & 1;
                if (tid < 32) pbuf[lb][(orow & 127) * 32 + j] = p;
                if (tid == 0) cbuf[lb][orow & 127] = C;
                if ((i & 7) == 0) {
                    float ss; RLSUM32(ss, p);
                    p = p / ss; C += (double)__logf(ss);
                }
            }
            if (c < 3) {
                STAGE(2 - c);                               // rows (2-c)*128 .. +127
                eraw = ebuf[(2 - c) & 1][127 * 32 + j];     // re-seed: row (2-c)*128+127
            }
            FLUSHPC(pb, Cb, 3 - c);
        }
    } else {
        // ---- viterbi (exact reference semantics; e from LDS, hist in LDS) ----
        unsigned char* hist = (unsigned char*)pbuf;   // (SEQ-1)*T = 16352 B

        float trv[32];
        #pragma unroll
        for (int n = 0; n < 32; ++n) trv[n] = trans[n * T + j];

        STAGE(0);
        float sc = start[j] + ebuf[0][j];

        for (int c = 0; c < 4; ++c) {
            int i0 = c ? c * 128 : 1, i1 = c * 128 + 127;
            for (int i = i0; i <= i1; ++i) {
                float ej = ebuf[c & 1][(i & 127) * 32 + j];
                float c_[32];
                #pragma unroll
                for (int n = 0; n < 32; ++n)
                    c_[n] = (rlf(sc, n) + trv[n]) + ej;
                float v1[16]; int i1_[16];
                #pragma unroll
                for (int n = 0; n < 16; ++n) {
                    bool t = c_[2 * n] >= c_[2 * n + 1];
                    v1[n] = t ? c_[2 * n] : c_[2 * n + 1];
                    i1_[n] = t ? 2 * n : 2 * n + 1;
                }
                float v2[8]; int i2[8];
                #pragma unroll
                for (int n = 0; n < 8; ++n) {
                    bool t = v1[2 * n] >= v1[2 * n + 1];
                    v2[n] = t ? v1[2 * n] : v1[2 * n + 1];
                    i2[n] = t ? i1_[2 * n] : i1_[2 * n + 1];
                }
                float v3[4]; int i3[4];
                #pragma unroll
                for (int n = 0; n < 4; ++n) {
                    bool t = v2[2 * n] >= v2[2 * n + 1];
                    v3[n] = t ? v2[2 * n] : v2[2 * n + 1];
                    i3[n] = t ? i2[2 * n] : i2[2 * n + 1];
                }
                float v4[2]; int i4[2];
                #pragma unroll
                for (int n = 0; n < 2; ++n) {
                    bool t = v3[2 * n] >= v3[2 * n + 1];
                    v4[n] = t ? v3[2 * n] : v3[2 * n + 1];
                    i4[n] = t ? i3[2 * n] : i3[2 * n + 1];
                }
                bool t = v4[0] >= v4[1];
                float best = t ? v4[0] : v4[1];
                int bi = t ? i4[0] : i4[1];

                if (tid < 32) hist[(i - 1) * T + j] = (unsigned char)bi;
                if (MB(ma, i)) sc = best;
            }
            if (c < 3) STAGE(c + 1);
        }
        // last = argmax_j(score + end), first index on ties
        float fs = sc + endp[j];
        int fj = j;
        #pragma unroll
        for (int d = 1; d < 32; d <<= 1) {
            float ov = __shfl_xor(fs, d);
            int oj = __shfl_xor(fj, d);
            if (ov > fs || (ov == fs && oj < fj)) { fs = ov; fj = oj; }
        }
        if (tid == 0) {
            int tag = fj;
            tagbuf[SEQ - 1] = tag;
            for (int i = SEQ - 2; i >= 0; --i) {
                tag = hist[i * T + tag];
                tagbuf[i] = tag;
            }
        }
        __syncthreads();
        #pragma unroll
        for (int k2 = 0; k2 < 8; ++k2) {
            int idx = k2 * 64 + tid;
            tags_out[(size_t)idx * BATCH + b] = (float)tagbuf[idx];
        }
    }
}

// ---------------- probs = pa * pb * exp(Ca + Cb - z) ----------------
__global__ __launch_bounds__(256) void k_probs(const float* __restrict__ pa,
        const float* __restrict__ pb, const double* __restrict__ Ca,
        const double* __restrict__ Cb, const double* __restrict__ zd,
        float* __restrict__ out)
{
    int idx = blockIdx.x * 256 + threadIdx.x;   // float4 index, 524288 total
    int ib = idx >> 3;                          // (i*BATCH + b)
    int b = ib & (BATCH - 1);
    double ex = Ca[ib] + Cb[ib] - zd[b];
    double scl = exp(ex);
    float4 a = ((const float4*)pa)[idx];
    float4 c = ((const float4*)pb)[idx];
    float4 o;
    o.x = (float)((double)a.x * (double)c.x * scl);
    o.y = (float)((double)a.y * (double)c.y * scl);
    o.z = (float)((double)a.z * (double)c.z * scl);
    o.w = (float)((double)a.w * (double)c.w * scl);
    ((float4*)out)[idx] = o;
}

extern "C" void kernel_launch(void* const* d_in, const int* in_sizes, int n_in,
                              void* d_out, int out_size, void* d_ws, size_t ws_size,
                              hipStream_t stream) {
    const float* features = (const float*)d_in[0];
    const int*   mask     = (const int*)d_in[1];
    const float* W        = (const float*)d_in[2];
    const float* bias     = (const float*)d_in[3];
    const float* trans    = (const float*)d_in[4];
    const float* startp   = (const float*)d_in[5];
    const float* endp     = (const float*)d_in[6];

    char* ws = (char*)d_ws;
    double* Ca = (double*)(ws + 0);                      // 65536 doubles
    double* Cb = (double*)(ws + 524288);                 // 65536 doubles
    double* zd = (double*)(ws + 1048576);                // 128 doubles
    float*  Wt = (float*)(ws + 1049600);                 // 32768 floats
    float*  e  = (float*)(ws + 1180672);                 // 2097152 floats
    float*  pa = (float*)(ws + 9569280);                 // 2097152 floats
    float*  pb = (float*)(ws + 17957888);                // 2097152 floats

    float* probs_out = (float*)d_out;
    float* tags_out  = probs_out + (size_t)SEQ * BATCH * T;

    k_wt<<<128, 256, 0, stream>>>(W, Wt);
    k_emis<<<1024, 256, 0, stream>>>(features, Wt, bias, e);
    k_rec<<<384, 64, 0, stream>>>(e, mask, trans, startp, endp,
                                  pa, pb, Ca, Cb, zd, tags_out);
    k_probs<<<2048, 256, 0, stream>>>(pa, pb, Ca, Cb, zd, probs_out);
}